// Round 10
// baseline (292.366 us; speedup 1.0000x reference)
//
#include <hip/hip_runtime.h>
#include <math.h>

namespace {
constexpr int B_  = 64;
constexpr int T_  = 1380;
constexpr int XD_ = 96;
constexpr int HD_ = 192;
constexpr int CN_ = 345;
constexpr int CP_ = 384;                       // padded CN
constexpr int TP_ = 1392;                      // padded T for Hth rows
constexpr int TP2_ = 1408;                     // padded T for k12 K-dim (22*64)
constexpr int TH_ = 690;                       // T/2 (u-split in k3)
constexpr float SCALE_ = 0.00736569563735987f; // 1/sqrt(96*192)
}

typedef __attribute__((ext_vector_type(8))) short bf16x8;
typedef __attribute__((ext_vector_type(4))) float f32x4;
typedef unsigned short u16;
typedef unsigned int   u32;

__device__ __forceinline__ u16 f2bf(float f) {
    union { float f; u32 u; } c; c.f = f;
    u32 r = (c.u + 0x7fffu + ((c.u >> 16) & 1u)) >> 16;
    return (u16)r;
}
__device__ __forceinline__ float bf2f(u16 s) {
    union { u32 u; float f; } c; c.u = ((u32)s) << 16;
    return c.f;
}

// 16-lane (DPP row) rotate reductions — VALU, not DS pipe (vs __shfl_xor).
__device__ __forceinline__ float red16_max(float v) {
    int ti;
    ti = __builtin_amdgcn_update_dpp(0, __builtin_bit_cast(int, v), 0x128, 0xf, 0xf, true);
    v = fmaxf(v, __builtin_bit_cast(float, ti));
    ti = __builtin_amdgcn_update_dpp(0, __builtin_bit_cast(int, v), 0x124, 0xf, 0xf, true);
    v = fmaxf(v, __builtin_bit_cast(float, ti));
    ti = __builtin_amdgcn_update_dpp(0, __builtin_bit_cast(int, v), 0x122, 0xf, 0xf, true);
    v = fmaxf(v, __builtin_bit_cast(float, ti));
    ti = __builtin_amdgcn_update_dpp(0, __builtin_bit_cast(int, v), 0x121, 0xf, 0xf, true);
    v = fmaxf(v, __builtin_bit_cast(float, ti));
    return v;
}
__device__ __forceinline__ float red16_sum(float v) {
    int ti;
    ti = __builtin_amdgcn_update_dpp(0, __builtin_bit_cast(int, v), 0x128, 0xf, 0xf, true);
    v += __builtin_bit_cast(float, ti);
    ti = __builtin_amdgcn_update_dpp(0, __builtin_bit_cast(int, v), 0x124, 0xf, 0xf, true);
    v += __builtin_bit_cast(float, ti);
    ti = __builtin_amdgcn_update_dpp(0, __builtin_bit_cast(int, v), 0x122, 0xf, 0xf, true);
    v += __builtin_bit_cast(float, ti);
    ti = __builtin_amdgcn_update_dpp(0, __builtin_bit_cast(int, v), 0x121, 0xf, 0xf, true);
    v += __builtin_bit_cast(float, ti);
    return v;
}

// ---------------------------------------------------------------------------
// K0h: fused H prep — one read of H produces Hh/Hl ([b][u][h] bf16 hi/lo)
// and Hth ([b][h][u] bf16 hi, row stride TP_).  grid (22, 3, B).
// ---------------------------------------------------------------------------
__global__ __launch_bounds__(256) void k0_h(const float* __restrict__ Hg,
                                            u16* __restrict__ Hh,
                                            u16* __restrict__ Hl,
                                            u16* __restrict__ Hth) {
    __shared__ u16 til[64][68];
    const int tid = threadIdx.x;
    const int u0 = blockIdx.x * 64, h0 = blockIdx.y * 64, b = blockIdx.z;
#pragma unroll
    for (int i = 0; i < 8; i++) {
        int lin = i * 256 + tid;           // 0..2047
        int r = lin >> 5;                  // u row 0..63
        int cp = lin & 31;                 // float2 col
        int u = u0 + r, h = h0 + cp * 2;
        float2 v = make_float2(0.f, 0.f);
        if (u < T_) v = *(const float2*)(Hg + ((size_t)b * T_ + u) * HD_ + h);
        u16 hx = f2bf(v.x), hy = f2bf(v.y);
        u16 lx = f2bf(v.x - bf2f(hx)), ly = f2bf(v.y - bf2f(hy));
        if (u < T_) {
            *(u32*)(Hh + ((size_t)b * T_ + u) * HD_ + h) = (u32)hx | ((u32)hy << 16);
            *(u32*)(Hl + ((size_t)b * T_ + u) * HD_ + h) = (u32)lx | ((u32)ly << 16);
        }
        til[cp * 2][r]     = hx;
        til[cp * 2 + 1][r] = hy;
    }
    __syncthreads();
#pragma unroll
    for (int i = 0; i < 4; i++) {
        int lin = i * 256 + tid;
        int hh = lin >> 4, cc = lin & 15;
        int u = u0 + cc * 4;
        if (u + 4 <= T_) {
            ushort4 v;
            v.x = til[hh][cc * 4 + 0];
            v.y = til[hh][cc * 4 + 1];
            v.z = til[hh][cc * 4 + 2];
            v.w = til[hh][cc * 4 + 3];
            *(ushort4*)(Hth + ((size_t)b * HD_ + h0 + hh) * TP_ + u) = v;
        }
    }
}

// ---------------------------------------------------------------------------
// K0c: X -> Xth/Xtl [b][x][t] bf16 hi/lo, t padded to TP2_ with zeros.
// ---------------------------------------------------------------------------
__global__ __launch_bounds__(256) void k0_x(const float* __restrict__ Xg,
                                            u16* __restrict__ Xth,
                                            u16* __restrict__ Xtl) {
    __shared__ __align__(16) u16 tih[96][72];
    __shared__ __align__(16) u16 til[96][72];
    const int tid = threadIdx.x;
    const int t0 = blockIdx.x * 64, b = blockIdx.y;
#pragma unroll
    for (int i = 0; i < 24; i++) {
        int lin = i * 256 + tid;
        int r = lin / 96, x = lin % 96;
        float v = (t0 + r < T_) ? Xg[((size_t)b * T_ + t0 + r) * XD_ + x] : 0.f;
        u16 hi = f2bf(v);
        tih[x][r] = hi;
        til[x][r] = f2bf(v - bf2f(hi));
    }
    __syncthreads();
#pragma unroll
    for (int i = 0; i < 6; i++) {
        int id = i * 256 + tid;
        int buf = (id >= 768);
        int cid = buf ? id - 768 : id;
        int x = cid >> 3, col = cid & 7;
        uint4 v = *(const uint4*)&(buf ? til : tih)[x][col * 8];
        u16* dst = (buf ? Xtl : Xth) + ((size_t)b * XD_ + x) * TP2_ + t0 + col * 8;
        *(uint4*)dst = v;
    }
}

// ---------------------------------------------------------------------------
// K0d: W2 -> W2h/W2l [CP_][TP2_] bf16 hi/lo, zero padded both dims.
// ---------------------------------------------------------------------------
__global__ __launch_bounds__(256) void k0_w2(const float* __restrict__ W2g,
                                             u16* __restrict__ W2h,
                                             u16* __restrict__ W2l) {
    const int n = CP_ * (TP2_ / 2);
    for (int i = blockIdx.x * 256 + threadIdx.x; i < n; i += gridDim.x * 256) {
        int c = i / (TP2_ / 2), tc = i % (TP2_ / 2);
        int t = tc * 2;
        float v0 = 0.f, v1 = 0.f;
        if (c < CN_) {
            if (t < T_)     v0 = W2g[(size_t)c * T_ + t];
            if (t + 1 < T_) v1 = W2g[(size_t)c * T_ + t + 1];
        }
        u16 h0 = f2bf(v0), h1 = f2bf(v1);
        u16 l0 = f2bf(v0 - bf2f(h0)), l1 = f2bf(v1 - bf2f(h1));
        ((u32*)W2h)[i] = (u32)h0 | ((u32)h1 << 16);
        ((u32*)W2l)[i] = (u32)l0 | ((u32)l1 << 16);
    }
}

// ---------------------------------------------------------------------------
// K0e: W1 [x][h] -> W1th/W1tl [h][x] bf16 hi/lo (tiny).
// ---------------------------------------------------------------------------
__global__ __launch_bounds__(256) void k0_w1(const float* __restrict__ W1g,
                                             u16* __restrict__ W1th,
                                             u16* __restrict__ W1tl) {
    int i = blockIdx.x * 256 + threadIdx.x;
    if (i < HD_ * XD_) {
        int h = i / XD_, x = i % XD_;
        float v = W1g[(size_t)x * HD_ + h];
        u16 hi = f2bf(v);
        W1th[i] = hi;
        W1tl[i] = f2bf(v - bf2f(hi));
    }
}

// ---------------------------------------------------------------------------
// K12: unchanged (passed; gld_lds + counted vmcnt + dbuf).
// ---------------------------------------------------------------------------
__global__ __launch_bounds__(256, 1) void k12_mfma(const u16* __restrict__ W2h,
                                                   const u16* __restrict__ W2l,
                                                   const u16* __restrict__ Xth,
                                                   const u16* __restrict__ Xtl,
                                                   const u16* __restrict__ W1th,
                                                   const u16* __restrict__ W1tl,
                                                   u32* __restrict__ Ysi) {
    __shared__ __align__(16) u16 smem[49152];   // 96 KB = 2 bufs x 4 arrays x 96x64
    float* sZ = (float*)smem;                   // phase 2: 96 x 100 fp32 (38.4 KB, buf0 only)

    const int tid  = threadIdx.x;
    const int lane = tid & 63;
    const int w    = tid >> 6;            // 0..3: wave id == staging array id
    const int tx   = lane & 15;
    const int quad = lane >> 4;
    const int wr   = w >> 1;              // c-half (48 rows)
    const int wc2  = w & 1;               // x-half (48 cols)
    const int L    = blockIdx.x;
    const int xcd  = L & 7;
    const int slot = L >> 3;              // 0..31
    const int b    = xcd * 8 + (slot >> 2);
    const int c0   = (slot & 3) * 96;

    const u16* gsrc;
    size_t rowstart;
    if (w == 0)      { gsrc = W2h; rowstart = (size_t)c0; }
    else if (w == 1) { gsrc = W2l; rowstart = (size_t)c0; }
    else if (w == 2) { gsrc = Xth; rowstart = (size_t)b * XD_; }
    else             { gsrc = Xtl; rowstart = (size_t)b * XD_; }
    const int jg = (lane & 7) ^ ((lane >> 3) & 7);   // pre-swizzled source group

#define STAGE(bufsel, kk)                                                         \
    {                                                                             \
        u16* lb = smem + (bufsel) * 24576 + w * 6144;                             \
        _Pragma("unroll")                                                         \
        for (int i_ = 0; i_ < 12; i_++) {                                         \
            int row_ = i_ * 8 + (lane >> 3);                                      \
            const u16* gp_ = gsrc + (rowstart + row_) * TP2_ + (kk) + jg * 8;     \
            __builtin_amdgcn_global_load_lds(                                     \
                (const __attribute__((address_space(1))) u32*)(const void*)gp_,   \
                (__attribute__((address_space(3))) u32*)(void*)(lb + i_ * 512),   \
                16, 0, 0);                                                        \
        }                                                                         \
    }

    f32x4 accZ[3][3];
#pragma unroll
    for (int i = 0; i < 3; i++)
#pragma unroll
        for (int j = 0; j < 3; j++) accZ[i][j] = (f32x4){0.f, 0.f, 0.f, 0.f};

    STAGE(0, 0);
    for (int s = 0; s < 22; s++) {
        __builtin_amdgcn_sched_barrier(0);
        if (s < 21) {
            STAGE((s + 1) & 1, (s + 1) * 64);
            asm volatile("s_waitcnt vmcnt(12)" ::: "memory");  // cur tile landed
        } else {
            asm volatile("s_waitcnt vmcnt(0)" ::: "memory");
        }
        __builtin_amdgcn_s_barrier();
        __builtin_amdgcn_sched_barrier(0);
        const u16* bufp = smem + (s & 1) * 24576;
#pragma unroll
        for (int ks2 = 0; ks2 < 2; ks2++) {
            const int G = ks2 * 4 + quad;
            bf16x8 ah[3], al[3], bh3[3], bl3[3];
#pragma unroll
            for (int am = 0; am < 3; am++) {
                int row = wr * 48 + am * 16 + tx;
                int off = row * 64 + (G ^ (row & 7)) * 8;
                ah[am] = *(const bf16x8*)(bufp + off);
                al[am] = *(const bf16x8*)(bufp + 6144 + off);
            }
#pragma unroll
            for (int bn = 0; bn < 3; bn++) {
                int row = wc2 * 48 + bn * 16 + tx;
                int off = row * 64 + (G ^ (row & 7)) * 8;
                bh3[bn] = *(const bf16x8*)(bufp + 12288 + off);
                bl3[bn] = *(const bf16x8*)(bufp + 18432 + off);
            }
#pragma unroll
            for (int am = 0; am < 3; am++)
#pragma unroll
                for (int bn = 0; bn < 3; bn++) {
                    accZ[am][bn] = __builtin_amdgcn_mfma_f32_16x16x32_bf16(ah[am], bh3[bn], accZ[am][bn], 0, 0, 0);
                    accZ[am][bn] = __builtin_amdgcn_mfma_f32_16x16x32_bf16(ah[am], bl3[bn], accZ[am][bn], 0, 0, 0);
                    accZ[am][bn] = __builtin_amdgcn_mfma_f32_16x16x32_bf16(al[am], bh3[bn], accZ[am][bn], 0, 0, 0);
                }
        }
        asm volatile("s_waitcnt lgkmcnt(0)" ::: "memory");
        __builtin_amdgcn_sched_barrier(0);
        __builtin_amdgcn_s_barrier();
    }
#undef STAGE

    __builtin_amdgcn_sched_barrier(0);
#pragma unroll
    for (int am = 0; am < 3; am++)
#pragma unroll
        for (int bn = 0; bn < 3; bn++)
#pragma unroll
            for (int r = 0; r < 4; r++)
                sZ[(wr * 48 + am * 16 + quad * 4 + r) * 100 + wc2 * 48 + bn * 16 + tx] = accZ[am][bn][r];
    __syncthreads();

    bf16x8 A2h[3][3], A2l[3][3];
#pragma unroll
    for (int am = 0; am < 3; am++)
#pragma unroll
        for (int ks = 0; ks < 3; ks++) {
            const float* zrow = sZ + (wr * 48 + am * 16 + tx) * 100 + ks * 32 + quad * 8;
            bf16x8 vh, vl;
#pragma unroll
            for (int j = 0; j < 8; j++) {
                float v = zrow[j];
                u16 hi = f2bf(v);
                vh[j] = (short)hi;
                vl[j] = (short)f2bf(v - bf2f(hi));
            }
            A2h[am][ks] = vh; A2l[am][ks] = vl;
        }

    f32x4 accY[3][6];
#pragma unroll
    for (int i = 0; i < 3; i++)
#pragma unroll
        for (int j = 0; j < 6; j++) accY[i][j] = (f32x4){0.f, 0.f, 0.f, 0.f};
#pragma unroll
    for (int hn = 0; hn < 6; hn++) {
        const int hrow = wc2 * 96 + hn * 16 + tx;
#pragma unroll
        for (int ks = 0; ks < 3; ks++) {
            bf16x8 bh = *(const bf16x8*)(W1th + (size_t)hrow * XD_ + ks * 32 + quad * 8);
            bf16x8 bl = *(const bf16x8*)(W1tl + (size_t)hrow * XD_ + ks * 32 + quad * 8);
#pragma unroll
            for (int am = 0; am < 3; am++) {
                accY[am][hn] = __builtin_amdgcn_mfma_f32_16x16x32_bf16(A2h[am][ks], bh, accY[am][hn], 0, 0, 0);
                accY[am][hn] = __builtin_amdgcn_mfma_f32_16x16x32_bf16(A2h[am][ks], bl, accY[am][hn], 0, 0, 0);
                accY[am][hn] = __builtin_amdgcn_mfma_f32_16x16x32_bf16(A2l[am][ks], bh, accY[am][hn], 0, 0, 0);
            }
        }
    }

#pragma unroll
    for (int am = 0; am < 3; am++)
#pragma unroll
        for (int r = 0; r < 4; r++) {
            int c = c0 + wr * 48 + am * 16 + quad * 4 + r;
            if (c < CN_) {
                size_t base = ((size_t)b * CN_ + c) * HD_;
#pragma unroll
                for (int hn = 0; hn < 6; hn++) {
                    float y = SCALE_ * accY[am][hn][r];
                    u16 hi = f2bf(y);
                    u16 lo = f2bf(y - bf2f(hi));
                    Ysi[base + wc2 * 96 + hn * 16 + tx] = (u32)hi | ((u32)lo << 16);
                }
            }
        }
}

// ---------------------------------------------------------------------------
// K3: flash attention, producer/consumer wave specialization.  grid 256
// (1 block/CU), block 768 = 12 waves.  Waves 0-5 (producers): 32 c-rows
// each, GEMM1 + online softmax -> P/alpha to LDS.  Waves 6-11 (consumers):
// 32 c-rows each, PV of tile t-1 (1-tile pipeline).  ROUND-10 FIX: sP is
// 192 rows x 40 u16 = 15,360 B PER BUFFER (round 9 sized it 7,680 B ->
// buf1 overlapped buf0 + stomped alpha + OOB LDS -> NaN).  Layout now:
//   0       Hh dbuf  2x12288
//   24576   Hl dbuf  2x12288
//   49152   Ht 3buf  3x12288
//   86016   sP dbuf  2x15360
//   116736  alpha dbuf 2x768   -> total 118,272 B
// ---------------------------------------------------------------------------
__global__ __launch_bounds__(768, 3) void k3_mfma(const u32* __restrict__ Ysi,
                                                  const u16* __restrict__ Hh,
                                                  const u16* __restrict__ Hl,
                                                  const u16* __restrict__ Hth,
                                                  float* __restrict__ Op,
                                                  float* __restrict__ Ml,
                                                  float* __restrict__ Ll) {
    __shared__ __align__(16) u16 smem[59136];   // 118,272 B

    const int tid  = threadIdx.x;
    const int lane = tid & 63;
    const int w    = tid >> 6;            // 0..11
    const int tx   = lane & 15;
    const int quad = lane >> 4;
    const int L    = blockIdx.x;
    const int xcd  = L & 7;
    const int slot = L >> 3;              // 0..31
    const int gp   = xcd * 16 + (slot >> 1);   // (b,sp) pair, 0..127
    const int ct   = slot & 1;                 // c-tile half (192 rows)
    const int b    = gp >> 1;
    const int sp   = gp & 1;
    const int c0   = ct * 192;
    const int us   = sp * TH_, ue = us + TH_;

    // ---- staging descriptors: 36 gld_lds/iter, 3 per wave (round-8 proven).
    // insts 0-11 sHh, 12-23 sHl, 24-35 sHt; source chunk pre-swizzled.
    const char* srcp[3];
    u32 off0[3];
    const u32 incw = (u32)__builtin_amdgcn_readfirstlane((w < 8) ? (32 * HD_ * 2) : 64);
#pragma unroll
    for (int j = 0; j < 3; j++) {
        int k = w * 3 + j;
        u32 o;
        if (k < 24) {
            int arr = (k < 12) ? 0 : 1;
            int ii  = k - arr * 12;
            int cid = ii * 64 + lane;          // 0..767
            int u   = cid / 24, c1 = cid % 24;
            int c   = (c1 & ~7) | ((c1 & 7) ^ ((u >> 1) & 7));
            const u16* basep = (arr == 0 ? Hh : Hl) + (size_t)b * T_ * HD_;
            srcp[j] = (const char*)basep + ((size_t)(us + u) * HD_ + c * 8) * 2;
            o = (u32)(arr * 24576 + ii * 1024);
        } else {
            int ii  = k - 24;
            int cid = ii * 64 + lane;          // 0..767
            int h   = cid >> 2, c2 = cid & 3;
            int c   = c2 ^ ((h >> 2) & 3);
            const u16* basep = Hth + (size_t)b * HD_ * TP_;
            srcp[j] = (const char*)basep + ((size_t)h * TP_ + us + c * 8) * 2;
            o = (u32)(49152 + ii * 1024);
        }
        off0[j] = (u32)__builtin_amdgcn_readfirstlane((int)o);
    }

// Hh/Hl use 2-buffer select b2; Ht uses 3-buffer select b3 (per-wave uniform).
#define STAGE3(b2, b3)                                                            \
    {                                                                             \
        const u32 bofs_ = ((w < 8) ? (u32)(b2) : (u32)(b3)) * 12288u;             \
        _Pragma("unroll")                                                         \
        for (int j_ = 0; j_ < 3; j_++) {                                          \
            __builtin_amdgcn_global_load_lds(                                     \
                (const __attribute__((address_space(1))) u32*)(const void*)srcp[j_], \
                (__attribute__((address_space(3))) u32*)(void*)((char*)smem + off0[j_] + bofs_), \
                16, 0, 0);                                                        \
            srcp[j_] += incw;                                                     \
        }                                                                         \
    }

#define PVSTEP(tt)                                                                \
    {                                                                             \
        const int pb_ = (tt) & 1, h3_ = (tt) % 3;                                 \
        const float* aB_ = (const float*)((const char*)smem + 116736 + pb_ * 768);\
        f32x4 al0 = *(const f32x4*)(aB_ + cw * 32 + quad * 4);                    \
        f32x4 al1 = *(const f32x4*)(aB_ + cw * 32 + 16 + quad * 4);               \
        _Pragma("unroll")                                                         \
        for (int j_ = 0; j_ < 12; j_++) { accO[0][j_] *= al0; accO[1][j_] *= al1; } \
        const u16* sPc_ = smem + 43008 + pb_ * 7680;                              \
        bf16x8 pa0 = *(const bf16x8*)(sPc_ + (cw * 32 + tx) * 40 + quad * 8);     \
        bf16x8 pa1 = *(const bf16x8*)(sPc_ + (cw * 32 + 16 + tx) * 40 + quad * 8);\
        const u16* Htb_ = smem + 24576 + h3_ * 6144;                              \
        const int ctq_ = quad ^ ((tx >> 2) & 3);                                  \
        __builtin_amdgcn_s_setprio(1);                                            \
        _Pragma("unroll")                                                         \
        for (int j_ = 0; j_ < 12; j_++) {                                         \
            bf16x8 hb_ = *(const bf16x8*)(Htb_ + (j_ * 16 + tx) * 32 + ctq_ * 8); \
            accO[0][j_] = __builtin_amdgcn_mfma_f32_16x16x32_bf16(pa0, hb_, accO[0][j_], 0, 0, 0); \
            accO[1][j_] = __builtin_amdgcn_mfma_f32_16x16x32_bf16(pa1, hb_, accO[1][j_], 0, 0, 0); \
        }                                                                         \
        __builtin_amdgcn_s_setprio(0);                                            \
    }

    if (w < 6) {
        // ------------------------- PRODUCER -------------------------
        bf16x8 Ah2[2][6], Al2[2][6];
#pragma unroll
        for (int st = 0; st < 2; st++) {
            const int ar = c0 + w * 32 + st * 16 + tx;
            if (ar < CN_) {
                const u32* yi = Ysi + ((size_t)b * CN_ + ar) * HD_;
#pragma unroll
                for (int ks = 0; ks < 6; ks++) {
                    u32 vv[8];
                    *(uint4*)&vv[0] = *(const uint4*)(yi + ks * 32 + quad * 8);
                    *(uint4*)&vv[4] = *(const uint4*)(yi + ks * 32 + quad * 8 + 4);
                    bf16x8 hh, ll;
#pragma unroll
                    for (int j = 0; j < 8; j++) {
                        hh[j] = (short)(vv[j] & 0xffffu);
                        ll[j] = (short)(vv[j] >> 16);
                    }
                    Ah2[st][ks] = hh; Al2[st][ks] = ll;
                }
            } else {
#pragma unroll
                for (int ks = 0; ks < 6; ks++) { Ah2[st][ks] = (bf16x8)0; Al2[st][ks] = (bf16x8)0; }
            }
        }
        float m_s[2][4], l_s[2][4];
#pragma unroll
        for (int st = 0; st < 2; st++)
#pragma unroll
            for (int r = 0; r < 4; r++) { m_s[st][r] = -1e30f; l_s[st][r] = 0.f; }

        STAGE3(0, 0);
        for (int t = 0; t < 22; t++) {
            const int u0 = us + t * 32;
            __builtin_amdgcn_sched_barrier(0);
            if (t < 21) {
                STAGE3((t + 1) & 1, (t + 1) % 3);
                asm volatile("s_waitcnt vmcnt(3)" ::: "memory");
            } else {
                asm volatile("s_waitcnt vmcnt(0)" ::: "memory");
            }
            __builtin_amdgcn_s_barrier();
            __builtin_amdgcn_sched_barrier(0);

            const u16* Hhb = smem + (t & 1) * 6144;
            const u16* Hlb = smem + 12288 + (t & 1) * 6144;
            const int xr = (tx >> 1) & 7;
            f32x4 sv0[2], sv1[2];
#pragma unroll
            for (int half = 0; half < 2; half++) {
                f32x4 s0[2], s1[2];
#pragma unroll
                for (int st = 0; st < 2; st++) { s0[st] = (f32x4){0.f,0.f,0.f,0.f}; s1[st] = (f32x4){0.f,0.f,0.f,0.f}; }
                const int ub = half * 16 + tx;
                __builtin_amdgcn_s_setprio(1);
#pragma unroll
                for (int ks = 0; ks < 6; ks++) {
                    const int cc = ks * 4 + quad;
                    const int cs = (cc & ~7) | ((cc & 7) ^ xr);
                    const int ro = ub * 192 + cs * 8;
                    bf16x8 bh = *(const bf16x8*)(Hhb + ro);
                    bf16x8 bl = *(const bf16x8*)(Hlb + ro);
#pragma unroll
                    for (int st = 0; st < 2; st++) {
                        s0[st] = __builtin_amdgcn_mfma_f32_16x16x32_bf16(Ah2[st][ks], bh, s0[st], 0, 0, 0);
                        s1[st] = __builtin_amdgcn_mfma_f32_16x16x32_bf16(Ah2[st][ks], bl, s1[st], 0, 0, 0);
                        s1[st] = __builtin_amdgcn_mfma_f32_16x16x32_bf16(Al2[st][ks], bh, s1[st], 0, 0, 0);
                    }
                }
                __builtin_amdgcn_s_setprio(0);
                const bool ok = (u0 + ub) < ue;
#pragma unroll
                for (int st = 0; st < 2; st++)
#pragma unroll
                    for (int r = 0; r < 4; r++) {
                        float v = ok ? (s0[st][r] + s1[st][r]) : -1e30f;
                        if (half == 0) sv0[st][r] = v; else sv1[st][r] = v;
                    }
            }

            // online softmax (DPP reductions); write P + alpha for consumers
            u16*   sPb = smem + 43008 + (t & 1) * 7680;
            float* aB  = (float*)((char*)smem + 116736 + (t & 1) * 768);
#pragma unroll
            for (int st = 0; st < 2; st++)
#pragma unroll
                for (int r = 0; r < 4; r++) {
                    float mx = red16_max(fmaxf(sv0[st][r], sv1[st][r]));
                    float mn = fmaxf(m_s[st][r], mx);
                    float alpha = __expf(m_s[st][r] - mn);
                    float p0 = __expf(sv0[st][r] - mn);
                    float p1 = __expf(sv1[st][r] - mn);
                    const int row = w * 32 + st * 16 + quad * 4 + r;
                    sPb[row * 40 + tx]      = f2bf(p0);
                    sPb[row * 40 + 16 + tx] = f2bf(p1);
                    aB[row] = alpha;
                    float s = red16_sum(p0 + p1);
                    l_s[st][r] = l_s[st][r] * alpha + s;
                    m_s[st][r] = mn;
                }

            asm volatile("s_waitcnt lgkmcnt(0)" ::: "memory");
            __builtin_amdgcn_sched_barrier(0);
            __builtin_amdgcn_s_barrier();
        }
        if (tx == 0) {
#pragma unroll
            for (int st = 0; st < 2; st++)
#pragma unroll
                for (int r = 0; r < 4; r++) {
                    int c = c0 + w * 32 + st * 16 + quad * 4 + r;
                    if (c < CN_) {
                        size_t mi = ((size_t)sp * B_ + b) * CN_ + c;
                        Ml[mi] = m_s[st][r];
                        Ll[mi] = l_s[st][r];
                    }
                }
        }
    } else {
        // ------------------------- CONSUMER -------------------------
        const int cw = w - 6;                  // 0..5
        f32x4 accO[2][12];
#pragma unroll
        for (int st = 0; st < 2; st++)
#pragma unroll
            for (int j = 0; j < 12; j++) accO[st][j] = (f32x4){0.f, 0.f, 0.f, 0.f};

        STAGE3(0, 0);
        for (int t = 0; t < 22; t++) {
            __builtin_amdgcn_sched_barrier(0);
            if (t < 21) {
                STAGE3((t + 1) & 1, (t + 1) % 3);
                asm volatile("s_waitcnt vmcnt(3)" ::: "memory");
            } else {
                asm volatile("s_waitcnt vmcnt(0)" ::: "memory");
            }
            __builtin_amdgcn_s_barrier();
            __builtin_amdgcn_sched_barrier(0);

            if (t > 0) { PVSTEP(t - 1) }

            asm volatile("s_waitcnt lgkmcnt(0)" ::: "memory");
            __builtin_amdgcn_sched_barrier(0);
            __builtin_amdgcn_s_barrier();
        }
        // epilogue: PV of the final tile (written in iter 21, barrier-ordered)
        PVSTEP(21)

#pragma unroll
        for (int st = 0; st < 2; st++)
#pragma unroll
            for (int r = 0; r < 4; r++) {
                int c = c0 + cw * 32 + st * 16 + quad * 4 + r;
                if (c < CN_) {
                    float* orow = Op + (((size_t)sp * B_ + b) * CN_ + c) * HD_;
#pragma unroll
                    for (int j = 0; j < 12; j++) orow[j * 16 + tx] = accO[st][j][r];
                }
            }
    }
#undef STAGE3
#undef PVSTEP
}

// ---------------------------------------------------------------------------
// K4: merge the two u-half partials.
// ---------------------------------------------------------------------------
__global__ __launch_bounds__(192) void k_merge(const float* __restrict__ Op,
                                               const float* __restrict__ Ml,
                                               const float* __restrict__ Ll,
                                               float* __restrict__ out) {
    const int c = blockIdx.x, b = blockIdx.y, h = threadIdx.x;
    const size_t i0 = (size_t)b * CN_ + c;
    const size_t i1 = (size_t)B_ * CN_ + i0;
    float m0 = Ml[i0], m1 = Ml[i1];
    float l0 = Ll[i0], l1 = Ll[i1];
    float M  = fmaxf(m0, m1);
    float e0 = __expf(m0 - M), e1 = __expf(m1 - M);
    float L  = l0 * e0 + l1 * e1;
    float o0 = Op[i0 * HD_ + h], o1 = Op[i1 * HD_ + h];
    out[i0 * HD_ + h] = (o0 * e0 + o1 * e1) / L;
}

// ---------------------------------------------------------------------------
extern "C" void kernel_launch(void* const* d_in, const int* in_sizes, int n_in,
                              void* d_out, int out_size, void* d_ws, size_t ws_size,
                              hipStream_t stream) {
    const float* X  = (const float*)d_in[0];
    const float* H  = (const float*)d_in[1];
    const float* W1 = (const float*)d_in[2];
    const float* W2 = (const float*)d_in[3];
    float* out = (float*)d_out;

    char* ws = (char*)d_ws;
    u32*   Ysi  = (u32*)(ws);                    //  16,957,440 (interleaved hi|lo)
    u16*   Hh   = (u16*)(ws + 16957440);         //  33,914,880
    u16*   Hl   = (u16*)(ws + 50872320);         //  33,914,880
    u16*   Hth  = (u16*)(ws + 84787200);         //  34,209,792
    u16*   Xth  = (u16*)(ws + 118996992);        //  17,301,504  (aliased by Op later)
    u16*   Xtl  = (u16*)(ws + 136298496);        //  17,301,504
    float* Op   = (float*)(ws + 118996992);      //  33,914,880  (aliases Xth+Xtl; k12 done first)
    u16*   W2h  = (u16*)(ws + 153600000);        //   1,081,344
    u16*   W2l  = (u16*)(ws + 154681344);        //   1,081,344
    u16*   W1th = (u16*)(ws + 155762688);        //      36,864
    u16*   W1tl = (u16*)(ws + 155799552);        //      36,864
    float* Ml   = (float*)(ws + 155836416);      //     176,640
    float* Ll   = (float*)(ws + 156013056);      //     176,640  -> end 156,189,696

    k0_h    <<<dim3(22, 3, B_), 256, 0, stream>>>(H, Hh, Hl, Hth);
    k0_x    <<<dim3(22, B_),    256, 0, stream>>>(X, Xth, Xtl);
    k0_w2   <<<dim3(1056),      256, 0, stream>>>(W2, W2h, W2l);
    k0_w1   <<<dim3(72),        256, 0, stream>>>(W1, W1th, W1tl);
    k12_mfma<<<dim3(256),       256, 0, stream>>>(W2h, W2l, Xth, Xtl, W1th, W1tl, Ysi);
    k3_mfma <<<dim3(256),       768, 0, stream>>>(Ysi, Hh, Hl, Hth, Op, Ml, Ll);
    k_merge <<<dim3(CN_, B_),   192, 0, stream>>>(Op, Ml, Ll, out);
}

// Round 11
// 264.123 us; speedup vs baseline: 1.1069x; 1.1069x over previous
//
#include <hip/hip_runtime.h>
#include <math.h>

namespace {
constexpr int B_  = 64;
constexpr int T_  = 1380;
constexpr int XD_ = 96;
constexpr int HD_ = 192;
constexpr int CN_ = 345;
constexpr int CP_ = 384;                       // padded CN
constexpr int TP_ = 1392;                      // padded T for Hth rows
constexpr int TP2_ = 1408;                     // padded T for k12 K-dim (22*64)
constexpr int TH_ = 690;                       // T/2 (u-split in k3)
constexpr float SCALE_ = 0.00736569563735987f; // 1/sqrt(96*192)
}

typedef __attribute__((ext_vector_type(8))) short bf16x8;
typedef __attribute__((ext_vector_type(4))) float f32x4;
typedef unsigned short u16;
typedef unsigned int   u32;

__device__ __forceinline__ u16 f2bf(float f) {
    union { float f; u32 u; } c; c.f = f;
    u32 r = (c.u + 0x7fffu + ((c.u >> 16) & 1u)) >> 16;
    return (u16)r;
}
__device__ __forceinline__ float bf2f(u16 s) {
    union { u32 u; float f; } c; c.u = ((u32)s) << 16;
    return c.f;
}

// 16-lane (DPP row) rotate reductions — VALU, not DS pipe (vs __shfl_xor).
__device__ __forceinline__ float red16_max(float v) {
    int ti;
    ti = __builtin_amdgcn_update_dpp(0, __builtin_bit_cast(int, v), 0x128, 0xf, 0xf, true);
    v = fmaxf(v, __builtin_bit_cast(float, ti));
    ti = __builtin_amdgcn_update_dpp(0, __builtin_bit_cast(int, v), 0x124, 0xf, 0xf, true);
    v = fmaxf(v, __builtin_bit_cast(float, ti));
    ti = __builtin_amdgcn_update_dpp(0, __builtin_bit_cast(int, v), 0x122, 0xf, 0xf, true);
    v = fmaxf(v, __builtin_bit_cast(float, ti));
    ti = __builtin_amdgcn_update_dpp(0, __builtin_bit_cast(int, v), 0x121, 0xf, 0xf, true);
    v = fmaxf(v, __builtin_bit_cast(float, ti));
    return v;
}
__device__ __forceinline__ float red16_sum(float v) {
    int ti;
    ti = __builtin_amdgcn_update_dpp(0, __builtin_bit_cast(int, v), 0x128, 0xf, 0xf, true);
    v += __builtin_bit_cast(float, ti);
    ti = __builtin_amdgcn_update_dpp(0, __builtin_bit_cast(int, v), 0x124, 0xf, 0xf, true);
    v += __builtin_bit_cast(float, ti);
    ti = __builtin_amdgcn_update_dpp(0, __builtin_bit_cast(int, v), 0x122, 0xf, 0xf, true);
    v += __builtin_bit_cast(float, ti);
    ti = __builtin_amdgcn_update_dpp(0, __builtin_bit_cast(int, v), 0x121, 0xf, 0xf, true);
    v += __builtin_bit_cast(float, ti);
    return v;
}

// ---------------------------------------------------------------------------
// K0h (rewritten this round): H -> Hh/Hl/Hth with full-width memory ops.
// grid (22, 3, B).  Per block: 64u x 64h tile.  Loads 2xfloat4 (32B/lane),
// stores uint4 (16B) for Hh and Hl, uint4 (16B) Hth stores via LDS transpose.
// Round-10 k0_h did float2 loads + 4B u32 stores (quarter-width writes).
// ---------------------------------------------------------------------------
__global__ __launch_bounds__(256) void k0_h(const float* __restrict__ Hg,
                                            u16* __restrict__ Hh,
                                            u16* __restrict__ Hl,
                                            u16* __restrict__ Hth) {
    __shared__ u16 til[64][72];                 // [h_local][u_local+pad]
    const int tid = threadIdx.x;
    const int u0 = blockIdx.x * 64, h0 = blockIdx.y * 64, b = blockIdx.z;
#pragma unroll
    for (int i = 0; i < 2; i++) {
        int task = i * 256 + tid;               // 0..511
        int r = task >> 3;                      // u row 0..63
        int g = task & 7;                       // h group (8 h)
        int u = u0 + r;
        float4 va = make_float4(0.f, 0.f, 0.f, 0.f), vb = va;
        if (u < T_) {
            const float* p = Hg + ((size_t)b * T_ + u) * HD_ + h0 + g * 8;
            va = *(const float4*)p;
            vb = *(const float4*)(p + 4);
        }
        float f[8] = {va.x, va.y, va.z, va.w, vb.x, vb.y, vb.z, vb.w};
        u16 hi[8], lo[8];
#pragma unroll
        for (int k = 0; k < 8; k++) {
            hi[k] = f2bf(f[k]);
            lo[k] = f2bf(f[k] - bf2f(hi[k]));
        }
        if (u < T_) {
            size_t base = ((size_t)b * T_ + u) * HD_ + h0 + g * 8;
            *(uint4*)(Hh + base) = *(const uint4*)hi;
            *(uint4*)(Hl + base) = *(const uint4*)lo;
        }
#pragma unroll
        for (int k = 0; k < 8; k++) til[g * 8 + k][r] = hi[k];
    }
    __syncthreads();
#pragma unroll
    for (int i = 0; i < 2; i++) {
        int task = i * 256 + tid;               // 0..511
        int hh = task >> 3;                     // h row 0..63
        int ug = task & 7;                      // u group (8 u)
        int ub = u0 + ug * 8;
        u16* dst = Hth + ((size_t)b * HD_ + h0 + hh) * TP_ + ub;
        if (ub + 8 <= T_) {
            *(uint4*)dst = *(const uint4*)&til[hh][ug * 8];
        } else if (ub < T_) {
#pragma unroll
            for (int k = 0; k < 8; k++)
                if (ub + k < T_) dst[k] = til[hh][ug * 8 + k];
        }
    }
}

// ---------------------------------------------------------------------------
// K0c: X -> Xth/Xtl [b][x][t] bf16 hi/lo, t padded to TP2_ with zeros.
// Rewritten loads: float4 (was scalar 4B).  Store phase unchanged.
// ---------------------------------------------------------------------------
__global__ __launch_bounds__(256) void k0_x(const float* __restrict__ Xg,
                                            u16* __restrict__ Xth,
                                            u16* __restrict__ Xtl) {
    __shared__ __align__(16) u16 tih[96][72];
    __shared__ __align__(16) u16 til[96][72];
    const int tid = threadIdx.x;
    const int t0 = blockIdx.x * 64, b = blockIdx.y;
#pragma unroll
    for (int i = 0; i < 6; i++) {
        int task = i * 256 + tid;               // 0..1535
        int r = task / 24, xg = task % 24;      // r: t-row, xg: x group of 4
        float4 v = make_float4(0.f, 0.f, 0.f, 0.f);
        if (t0 + r < T_)
            v = *(const float4*)(Xg + ((size_t)b * T_ + t0 + r) * XD_ + xg * 4);
        float f[4] = {v.x, v.y, v.z, v.w};
#pragma unroll
        for (int k = 0; k < 4; k++) {
            u16 hi = f2bf(f[k]);
            tih[xg * 4 + k][r] = hi;
            til[xg * 4 + k][r] = f2bf(f[k] - bf2f(hi));
        }
    }
    __syncthreads();
#pragma unroll
    for (int i = 0; i < 6; i++) {
        int id = i * 256 + tid;
        int buf = (id >= 768);
        int cid = buf ? id - 768 : id;
        int x = cid >> 3, col = cid & 7;
        uint4 v = *(const uint4*)&(buf ? til : tih)[x][col * 8];
        u16* dst = (buf ? Xtl : Xth) + ((size_t)b * XD_ + x) * TP2_ + t0 + col * 8;
        *(uint4*)dst = v;
    }
}

// ---------------------------------------------------------------------------
// K0d: W2 -> W2h/W2l [CP_][TP2_] bf16 hi/lo, zero padded both dims.
// ---------------------------------------------------------------------------
__global__ __launch_bounds__(256) void k0_w2(const float* __restrict__ W2g,
                                             u16* __restrict__ W2h,
                                             u16* __restrict__ W2l) {
    const int n = CP_ * (TP2_ / 2);
    for (int i = blockIdx.x * 256 + threadIdx.x; i < n; i += gridDim.x * 256) {
        int c = i / (TP2_ / 2), tc = i % (TP2_ / 2);
        int t = tc * 2;
        float v0 = 0.f, v1 = 0.f;
        if (c < CN_) {
            if (t < T_)     v0 = W2g[(size_t)c * T_ + t];
            if (t + 1 < T_) v1 = W2g[(size_t)c * T_ + t + 1];
        }
        u16 h0 = f2bf(v0), h1 = f2bf(v1);
        u16 l0 = f2bf(v0 - bf2f(h0)), l1 = f2bf(v1 - bf2f(h1));
        ((u32*)W2h)[i] = (u32)h0 | ((u32)h1 << 16);
        ((u32*)W2l)[i] = (u32)l0 | ((u32)l1 << 16);
    }
}

// ---------------------------------------------------------------------------
// K0e: W1 [x][h] -> W1th/W1tl [h][x] bf16 hi/lo (tiny).
// ---------------------------------------------------------------------------
__global__ __launch_bounds__(256) void k0_w1(const float* __restrict__ W1g,
                                             u16* __restrict__ W1th,
                                             u16* __restrict__ W1tl) {
    int i = blockIdx.x * 256 + threadIdx.x;
    if (i < HD_ * XD_) {
        int h = i / XD_, x = i % XD_;
        float v = W1g[(size_t)x * HD_ + h];
        u16 hi = f2bf(v);
        W1th[i] = hi;
        W1tl[i] = f2bf(v - bf2f(hi));
    }
}

// ---------------------------------------------------------------------------
// K12: unchanged (passed; gld_lds + counted vmcnt + dbuf).
// ---------------------------------------------------------------------------
__global__ __launch_bounds__(256, 1) void k12_mfma(const u16* __restrict__ W2h,
                                                   const u16* __restrict__ W2l,
                                                   const u16* __restrict__ Xth,
                                                   const u16* __restrict__ Xtl,
                                                   const u16* __restrict__ W1th,
                                                   const u16* __restrict__ W1tl,
                                                   u32* __restrict__ Ysi) {
    __shared__ __align__(16) u16 smem[49152];   // 96 KB = 2 bufs x 4 arrays x 96x64
    float* sZ = (float*)smem;                   // phase 2: 96 x 100 fp32 (38.4 KB, buf0 only)

    const int tid  = threadIdx.x;
    const int lane = tid & 63;
    const int w    = tid >> 6;            // 0..3: wave id == staging array id
    const int tx   = lane & 15;
    const int quad = lane >> 4;
    const int wr   = w >> 1;              // c-half (48 rows)
    const int wc2  = w & 1;               // x-half (48 cols)
    const int L    = blockIdx.x;
    const int xcd  = L & 7;
    const int slot = L >> 3;              // 0..31
    const int b    = xcd * 8 + (slot >> 2);
    const int c0   = (slot & 3) * 96;

    const u16* gsrc;
    size_t rowstart;
    if (w == 0)      { gsrc = W2h; rowstart = (size_t)c0; }
    else if (w == 1) { gsrc = W2l; rowstart = (size_t)c0; }
    else if (w == 2) { gsrc = Xth; rowstart = (size_t)b * XD_; }
    else             { gsrc = Xtl; rowstart = (size_t)b * XD_; }
    const int jg = (lane & 7) ^ ((lane >> 3) & 7);   // pre-swizzled source group

#define STAGE(bufsel, kk)                                                         \
    {                                                                             \
        u16* lb = smem + (bufsel) * 24576 + w * 6144;                             \
        _Pragma("unroll")                                                         \
        for (int i_ = 0; i_ < 12; i_++) {                                         \
            int row_ = i_ * 8 + (lane >> 3);                                      \
            const u16* gp_ = gsrc + (rowstart + row_) * TP2_ + (kk) + jg * 8;     \
            __builtin_amdgcn_global_load_lds(                                     \
                (const __attribute__((address_space(1))) u32*)(const void*)gp_,   \
                (__attribute__((address_space(3))) u32*)(void*)(lb + i_ * 512),   \
                16, 0, 0);                                                        \
        }                                                                         \
    }

    f32x4 accZ[3][3];
#pragma unroll
    for (int i = 0; i < 3; i++)
#pragma unroll
        for (int j = 0; j < 3; j++) accZ[i][j] = (f32x4){0.f, 0.f, 0.f, 0.f};

    STAGE(0, 0);
    for (int s = 0; s < 22; s++) {
        __builtin_amdgcn_sched_barrier(0);
        if (s < 21) {
            STAGE((s + 1) & 1, (s + 1) * 64);
            asm volatile("s_waitcnt vmcnt(12)" ::: "memory");  // cur tile landed
        } else {
            asm volatile("s_waitcnt vmcnt(0)" ::: "memory");
        }
        __builtin_amdgcn_s_barrier();
        __builtin_amdgcn_sched_barrier(0);
        const u16* bufp = smem + (s & 1) * 24576;
#pragma unroll
        for (int ks2 = 0; ks2 < 2; ks2++) {
            const int G = ks2 * 4 + quad;
            bf16x8 ah[3], al[3], bh3[3], bl3[3];
#pragma unroll
            for (int am = 0; am < 3; am++) {
                int row = wr * 48 + am * 16 + tx;
                int off = row * 64 + (G ^ (row & 7)) * 8;
                ah[am] = *(const bf16x8*)(bufp + off);
                al[am] = *(const bf16x8*)(bufp + 6144 + off);
            }
#pragma unroll
            for (int bn = 0; bn < 3; bn++) {
                int row = wc2 * 48 + bn * 16 + tx;
                int off = row * 64 + (G ^ (row & 7)) * 8;
                bh3[bn] = *(const bf16x8*)(bufp + 12288 + off);
                bl3[bn] = *(const bf16x8*)(bufp + 18432 + off);
            }
#pragma unroll
            for (int am = 0; am < 3; am++)
#pragma unroll
                for (int bn = 0; bn < 3; bn++) {
                    accZ[am][bn] = __builtin_amdgcn_mfma_f32_16x16x32_bf16(ah[am], bh3[bn], accZ[am][bn], 0, 0, 0);
                    accZ[am][bn] = __builtin_amdgcn_mfma_f32_16x16x32_bf16(ah[am], bl3[bn], accZ[am][bn], 0, 0, 0);
                    accZ[am][bn] = __builtin_amdgcn_mfma_f32_16x16x32_bf16(al[am], bh3[bn], accZ[am][bn], 0, 0, 0);
                }
        }
        asm volatile("s_waitcnt lgkmcnt(0)" ::: "memory");
        __builtin_amdgcn_sched_barrier(0);
        __builtin_amdgcn_s_barrier();
    }
#undef STAGE

    __builtin_amdgcn_sched_barrier(0);
#pragma unroll
    for (int am = 0; am < 3; am++)
#pragma unroll
        for (int bn = 0; bn < 3; bn++)
#pragma unroll
            for (int r = 0; r < 4; r++)
                sZ[(wr * 48 + am * 16 + quad * 4 + r) * 100 + wc2 * 48 + bn * 16 + tx] = accZ[am][bn][r];
    __syncthreads();

    bf16x8 A2h[3][3], A2l[3][3];
#pragma unroll
    for (int am = 0; am < 3; am++)
#pragma unroll
        for (int ks = 0; ks < 3; ks++) {
            const float* zrow = sZ + (wr * 48 + am * 16 + tx) * 100 + ks * 32 + quad * 8;
            bf16x8 vh, vl;
#pragma unroll
            for (int j = 0; j < 8; j++) {
                float v = zrow[j];
                u16 hi = f2bf(v);
                vh[j] = (short)hi;
                vl[j] = (short)f2bf(v - bf2f(hi));
            }
            A2h[am][ks] = vh; A2l[am][ks] = vl;
        }

    f32x4 accY[3][6];
#pragma unroll
    for (int i = 0; i < 3; i++)
#pragma unroll
        for (int j = 0; j < 6; j++) accY[i][j] = (f32x4){0.f, 0.f, 0.f, 0.f};
#pragma unroll
    for (int hn = 0; hn < 6; hn++) {
        const int hrow = wc2 * 96 + hn * 16 + tx;
#pragma unroll
        for (int ks = 0; ks < 3; ks++) {
            bf16x8 bh = *(const bf16x8*)(W1th + (size_t)hrow * XD_ + ks * 32 + quad * 8);
            bf16x8 bl = *(const bf16x8*)(W1tl + (size_t)hrow * XD_ + ks * 32 + quad * 8);
#pragma unroll
            for (int am = 0; am < 3; am++) {
                accY[am][hn] = __builtin_amdgcn_mfma_f32_16x16x32_bf16(A2h[am][ks], bh, accY[am][hn], 0, 0, 0);
                accY[am][hn] = __builtin_amdgcn_mfma_f32_16x16x32_bf16(A2h[am][ks], bl, accY[am][hn], 0, 0, 0);
                accY[am][hn] = __builtin_amdgcn_mfma_f32_16x16x32_bf16(A2l[am][ks], bh, accY[am][hn], 0, 0, 0);
            }
        }
    }

#pragma unroll
    for (int am = 0; am < 3; am++)
#pragma unroll
        for (int r = 0; r < 4; r++) {
            int c = c0 + wr * 48 + am * 16 + quad * 4 + r;
            if (c < CN_) {
                size_t base = ((size_t)b * CN_ + c) * HD_;
#pragma unroll
                for (int hn = 0; hn < 6; hn++) {
                    float y = SCALE_ * accY[am][hn][r];
                    u16 hi = f2bf(y);
                    u16 lo = f2bf(y - bf2f(hi));
                    Ysi[base + wc2 * 96 + hn * 16 + tx] = (u32)hi | ((u32)lo << 16);
                }
            }
        }
}

// ---------------------------------------------------------------------------
// K3: REVERTED to round-8 symmetric 12-wave version (75 µs, passed).
// Round 10's producer/consumer split regressed to 82 µs (load imbalance:
// producer path ~2x consumer path -> consumers idle at barriers).
// grid 256 = 1 block/CU; block 768 = 12 waves, two c-tiles (192 rows) of
// one (b,sp) pair share one H staging.  36 gld_lds/iter = 3/wave, vmcnt(3).
// ---------------------------------------------------------------------------
__global__ __launch_bounds__(768, 3) void k3_mfma(const u32* __restrict__ Ysi,
                                                  const u16* __restrict__ Hh,
                                                  const u16* __restrict__ Hl,
                                                  const u16* __restrict__ Hth,
                                                  float* __restrict__ Op,
                                                  float* __restrict__ Ml,
                                                  float* __restrict__ Ll) {
    __shared__ __align__(16) u16 smem[44544];   // 89,088 B: 73,728 H-dbuf + 15,360 sP

    const int tid  = threadIdx.x;
    const int lane = tid & 63;
    const int w    = tid >> 6;            // 0..11
    const int tx   = lane & 15;
    const int quad = lane >> 4;
    const int L    = blockIdx.x;
    const int xcd  = L & 7;
    const int slot = L >> 3;              // 0..31
    const int gp   = xcd * 16 + (slot >> 1);   // (b,sp) pair, 0..127
    const int ct   = slot & 1;                 // c-tile half (192 rows)
    const int b    = gp >> 1;
    const int sp   = gp & 1;
    const int c0   = ct * 192;
    const int us   = sp * TH_, ue = us + TH_;

    // ---- A-operand from interleaved Ysi (unpack once)
    bf16x8 Ah[6], Al[6];
    const int ar = c0 + w * 16 + tx;
    if (ar < CN_) {
        const u32* yi = Ysi + ((size_t)b * CN_ + ar) * HD_;
#pragma unroll
        for (int ks = 0; ks < 6; ks++) {
            u32 vv[8];
            *(uint4*)&vv[0] = *(const uint4*)(yi + ks * 32 + quad * 8);
            *(uint4*)&vv[4] = *(const uint4*)(yi + ks * 32 + quad * 8 + 4);
            bf16x8 hh, ll;
#pragma unroll
            for (int j = 0; j < 8; j++) {
                hh[j] = (short)(vv[j] & 0xffffu);
                ll[j] = (short)(vv[j] >> 16);
            }
            Ah[ks] = hh; Al[ks] = ll;
        }
    } else {
#pragma unroll
        for (int ks = 0; ks < 6; ks++) { Ah[ks] = (bf16x8)0; Al[ks] = (bf16x8)0; }
    }

    float m_s[4], l_s[4];
    f32x4 accO[12];
#pragma unroll
    for (int r = 0; r < 4; r++) { m_s[r] = -1e30f; l_s[r] = 0.f; }
#pragma unroll
    for (int j = 0; j < 12; j++) accO[j] = (f32x4){0.f, 0.f, 0.f, 0.f};

    // ---- per-lane staging descriptors: 36 gld_lds/iter, 3 per wave.
    const char* srcp[3];
    u32 off0[3];
    const u32 incw = (u32)__builtin_amdgcn_readfirstlane((w < 8) ? (32 * HD_ * 2) : 64);
#pragma unroll
    for (int j = 0; j < 3; j++) {
        int k = w * 3 + j;
        u32 o;
        if (k < 24) {
            int arr = (k < 12) ? 0 : 1;
            int ii  = k - arr * 12;
            int cid = ii * 64 + lane;          // 0..767
            int u   = cid / 24, c1 = cid % 24;
            int c   = (c1 & ~7) | ((c1 & 7) ^ ((u >> 1) & 7));
            const u16* basep = (arr == 0 ? Hh : Hl) + (size_t)b * T_ * HD_;
            srcp[j] = (const char*)basep + ((size_t)(us + u) * HD_ + c * 8) * 2;
            o = (u32)(arr * 24576 + ii * 1024);
        } else {
            int ii  = k - 24;
            int cid = ii * 64 + lane;          // 0..767
            int h   = cid >> 2, c2 = cid & 3;
            int c   = c2 ^ ((h >> 2) & 3);
            const u16* basep = Hth + (size_t)b * HD_ * TP_;
            srcp[j] = (const char*)basep + ((size_t)h * TP_ + us + c * 8) * 2;
            o = (u32)(49152 + ii * 1024);
        }
        off0[j] = (u32)__builtin_amdgcn_readfirstlane((int)o);
    }

#define STAGE3(bufsel)                                                            \
    {                                                                             \
        _Pragma("unroll")                                                         \
        for (int j_ = 0; j_ < 3; j_++) {                                          \
            __builtin_amdgcn_global_load_lds(                                     \
                (const __attribute__((address_space(1))) u32*)(const void*)srcp[j_], \
                (__attribute__((address_space(3))) u32*)(void*)((char*)smem + off0[j_] + (bufsel) * 12288), \
                16, 0, 0);                                                        \
            srcp[j_] += incw;                                                     \
        }                                                                         \
    }

    u16* sPb = smem + 36864;                   // 192 x 40 u16 (byte 73,728)

    STAGE3(0);                                  // tile 0 -> buf 0
    for (int t = 0; t < 22; t++) {
        const int u0  = us + t * 32;
        const int buf = t & 1;
        __builtin_amdgcn_sched_barrier(0);
        if (t < 21) {
            STAGE3(buf ^ 1);                    // tile t+1 -> other buf
            asm volatile("s_waitcnt vmcnt(3)" ::: "memory");   // tile t landed
        } else {
            asm volatile("s_waitcnt vmcnt(0)" ::: "memory");
        }
        __builtin_amdgcn_s_barrier();
        __builtin_amdgcn_sched_barrier(0);

        const u16* Hhb = smem + buf * 6144;
        const u16* Hlb = smem + 12288 + buf * 6144;
        const u16* Htb = smem + 24576 + buf * 6144;

        // ---- GEMM1: S[c][u], K=192, split-bf16 (hi*hi + hi*lo + lo*hi)
        f32x4 s0a = {0.f, 0.f, 0.f, 0.f}, s1a = {0.f, 0.f, 0.f, 0.f};
        f32x4 s0b = {0.f, 0.f, 0.f, 0.f}, s1b = {0.f, 0.f, 0.f, 0.f};
        const int xr = (tx >> 1) & 7;           // same for row tx and 16+tx
        __builtin_amdgcn_s_setprio(1);
#pragma unroll
        for (int ks = 0; ks < 6; ks++) {
            const int cc = ks * 4 + quad;
            const int cs = (cc & ~7) | ((cc & 7) ^ xr);
            const int ro0 = tx * 192 + cs * 8;
            const int ro1 = (16 + tx) * 192 + cs * 8;
            bf16x8 bh0 = *(const bf16x8*)(Hhb + ro0);
            bf16x8 bl0 = *(const bf16x8*)(Hlb + ro0);
            bf16x8 bh1 = *(const bf16x8*)(Hhb + ro1);
            bf16x8 bl1 = *(const bf16x8*)(Hlb + ro1);
            s0a = __builtin_amdgcn_mfma_f32_16x16x32_bf16(Ah[ks], bh0, s0a, 0, 0, 0);
            s1a = __builtin_amdgcn_mfma_f32_16x16x32_bf16(Ah[ks], bl0, s1a, 0, 0, 0);
            s1a = __builtin_amdgcn_mfma_f32_16x16x32_bf16(Al[ks], bh0, s1a, 0, 0, 0);
            s0b = __builtin_amdgcn_mfma_f32_16x16x32_bf16(Ah[ks], bh1, s0b, 0, 0, 0);
            s1b = __builtin_amdgcn_mfma_f32_16x16x32_bf16(Ah[ks], bl1, s1b, 0, 0, 0);
            s1b = __builtin_amdgcn_mfma_f32_16x16x32_bf16(Al[ks], bh1, s1b, 0, 0, 0);
        }
        __builtin_amdgcn_s_setprio(0);
        float sv0[4], sv1[4];
        const bool okA = (u0 + tx) < ue, okB = (u0 + 16 + tx) < ue;
#pragma unroll
        for (int r = 0; r < 4; r++) {
            sv0[r] = okA ? (s0a[r] + s1a[r]) : -1e30f;
            sv1[r] = okB ? (s0b[r] + s1b[r]) : -1e30f;
        }

        // ---- online softmax; 16-lane reductions via DPP (VALU, no DS)
        float alpha[4];
#pragma unroll
        for (int r = 0; r < 4; r++) {
            float mx = red16_max(fmaxf(sv0[r], sv1[r]));
            float mn = fmaxf(m_s[r], mx);
            alpha[r] = __expf(m_s[r] - mn);
            float p0 = __expf(sv0[r] - mn);
            float p1 = __expf(sv1[r] - mn);
            sPb[(w * 16 + quad * 4 + r) * 40 + tx]      = f2bf(p0);
            sPb[(w * 16 + quad * 4 + r) * 40 + 16 + tx] = f2bf(p1);
            float s = red16_sum(p0 + p1);
            l_s[r] = l_s[r] * alpha[r] + s;
            m_s[r] = mn;
        }
        f32x4 alv = {alpha[0], alpha[1], alpha[2], alpha[3]};
#pragma unroll
        for (int j = 0; j < 12; j++) accO[j] *= alv;

        // ---- PV: O += P * H, K=32.  sP rows are wave-private (in-order DS).
        bf16x8 pa = *(const bf16x8*)(sPb + (w * 16 + tx) * 40 + quad * 8);
        const int ctq = quad ^ ((tx >> 2) & 3);
        __builtin_amdgcn_s_setprio(1);
#pragma unroll
        for (int j = 0; j < 12; j++) {
            bf16x8 hb = *(const bf16x8*)(Htb + (j * 16 + tx) * 32 + ctq * 8);
            accO[j] = __builtin_amdgcn_mfma_f32_16x16x32_bf16(pa, hb, accO[j], 0, 0, 0);
        }
        __builtin_amdgcn_s_setprio(0);

        // all LDS reads of buf done before any wave stages into it next iter
        asm volatile("s_waitcnt lgkmcnt(0)" ::: "memory");
        __builtin_amdgcn_sched_barrier(0);
        __builtin_amdgcn_s_barrier();
    }
#undef STAGE3

#pragma unroll
    for (int r = 0; r < 4; r++) {
        int c = c0 + w * 16 + quad * 4 + r;
        if (c < CN_) {
            float* orow = Op + (((size_t)sp * B_ + b) * CN_ + c) * HD_;
#pragma unroll
            for (int j = 0; j < 12; j++) orow[j * 16 + tx] = accO[j][r];
            if (tx == 0) {
                size_t mi = ((size_t)sp * B_ + b) * CN_ + c;
                Ml[mi] = m_s[r];
                Ll[mi] = l_s[r];
            }
        }
    }
}

// ---------------------------------------------------------------------------
// K4: merge the two u-half partials — float4-vectorized grid-stride.
// ---------------------------------------------------------------------------
__global__ __launch_bounds__(256) void k_merge(const float* __restrict__ Op,
                                               const float* __restrict__ Ml,
                                               const float* __restrict__ Ll,
                                               float* __restrict__ out) {
    const int total = B_ * CN_ * (HD_ / 4);     // 1,059,840 float4 tasks
    for (int i = blockIdx.x * 256 + threadIdx.x; i < total; i += gridDim.x * 256) {
        int f  = i % (HD_ / 4);
        int bc = i / (HD_ / 4);                 // b*CN_ + c
        const size_t i0 = (size_t)bc;
        const size_t i1 = (size_t)B_ * CN_ + i0;
        float m0 = Ml[i0], m1 = Ml[i1];
        float l0 = Ll[i0], l1 = Ll[i1];
        float M  = fmaxf(m0, m1);
        float e0 = __expf(m0 - M), e1 = __expf(m1 - M);
        float inv = 1.0f / (l0 * e0 + l1 * e1);
        float4 o0 = *(const float4*)(Op + i0 * HD_ + f * 4);
        float4 o1 = *(const float4*)(Op + i1 * HD_ + f * 4);
        float4 r;
        r.x = (o0.x * e0 + o1.x * e1) * inv;
        r.y = (o0.y * e0 + o1.y * e1) * inv;
        r.z = (o0.z * e0 + o1.z * e1) * inv;
        r.w = (o0.w * e0 + o1.w * e1) * inv;
        *(float4*)(out + i0 * HD_ + f * 4) = r;
    }
}

// ---------------------------------------------------------------------------
extern "C" void kernel_launch(void* const* d_in, const int* in_sizes, int n_in,
                              void* d_out, int out_size, void* d_ws, size_t ws_size,
                              hipStream_t stream) {
    const float* X  = (const float*)d_in[0];
    const float* H  = (const float*)d_in[1];
    const float* W1 = (const float*)d_in[2];
    const float* W2 = (const float*)d_in[3];
    float* out = (float*)d_out;

    char* ws = (char*)d_ws;
    u32*   Ysi  = (u32*)(ws);                    //  16,957,440 (interleaved hi|lo)
    u16*   Hh   = (u16*)(ws + 16957440);         //  33,914,880
    u16*   Hl   = (u16*)(ws + 50872320);         //  33,914,880
    u16*   Hth  = (u16*)(ws + 84787200);         //  34,209,792
    u16*   Xth  = (u16*)(ws + 118996992);        //  17,301,504  (aliased by Op later)
    u16*   Xtl  = (u16*)(ws + 136298496);        //  17,301,504
    float* Op   = (float*)(ws + 118996992);      //  33,914,880  (aliases Xth+Xtl; k12 done first)
    u16*   W2h  = (u16*)(ws + 153600000);        //   1,081,344
    u16*   W2l  = (u16*)(ws + 154681344);        //   1,081,344
    u16*   W1th = (u16*)(ws + 155762688);        //      36,864
    u16*   W1tl = (u16*)(ws + 155799552);        //      36,864
    float* Ml   = (float*)(ws + 155836416);      //     176,640
    float* Ll   = (float*)(ws + 156013056);      //     176,640  -> end 156,189,696

    k0_h    <<<dim3(22, 3, B_), 256, 0, stream>>>(H, Hh, Hl, Hth);
    k0_x    <<<dim3(22, B_),    256, 0, stream>>>(X, Xth, Xtl);
    k0_w2   <<<dim3(1056),      256, 0, stream>>>(W2, W2h, W2l);
    k0_w1   <<<dim3(72),        256, 0, stream>>>(W1, W1th, W1tl);
    k12_mfma<<<dim3(256),       256, 0, stream>>>(W2h, W2l, Xth, Xtl, W1th, W1tl, Ysi);
    k3_mfma <<<dim3(256),       768, 0, stream>>>(Ysi, Hh, Hl, Hth, Op, Ml, Ll);
    k_merge <<<dim3(2048),      256, 0, stream>>>(Op, Ml, Ll, out);
}

// Round 12
// 255.745 us; speedup vs baseline: 1.1432x; 1.0328x over previous
//
#include <hip/hip_runtime.h>
#include <math.h>

namespace {
constexpr int B_  = 64;
constexpr int T_  = 1380;
constexpr int XD_ = 96;
constexpr int HD_ = 192;
constexpr int CN_ = 345;
constexpr int CP_ = 384;                       // padded CN
constexpr int TP_ = 1392;                      // padded T for Hth rows
constexpr int TP2_ = 1408;                     // padded T for k12 K-dim (22*64)
constexpr int TH_ = 690;                       // T/2 (u-split in k3)
constexpr float SCALE_ = 0.00736569563735987f; // 1/sqrt(96*192)
}

typedef __attribute__((ext_vector_type(8))) short bf16x8;
typedef __attribute__((ext_vector_type(4))) float f32x4;
typedef unsigned short u16;
typedef unsigned int   u32;

__device__ __forceinline__ u16 f2bf(float f) {
    union { float f; u32 u; } c; c.f = f;
    u32 r = (c.u + 0x7fffu + ((c.u >> 16) & 1u)) >> 16;
    return (u16)r;
}
__device__ __forceinline__ float bf2f(u16 s) {
    union { u32 u; float f; } c; c.u = ((u32)s) << 16;
    return c.f;
}

// 16-lane (DPP row) rotate reductions — VALU, not DS pipe (vs __shfl_xor).
__device__ __forceinline__ float red16_max(float v) {
    int ti;
    ti = __builtin_amdgcn_update_dpp(0, __builtin_bit_cast(int, v), 0x128, 0xf, 0xf, true);
    v = fmaxf(v, __builtin_bit_cast(float, ti));
    ti = __builtin_amdgcn_update_dpp(0, __builtin_bit_cast(int, v), 0x124, 0xf, 0xf, true);
    v = fmaxf(v, __builtin_bit_cast(float, ti));
    ti = __builtin_amdgcn_update_dpp(0, __builtin_bit_cast(int, v), 0x122, 0xf, 0xf, true);
    v = fmaxf(v, __builtin_bit_cast(float, ti));
    ti = __builtin_amdgcn_update_dpp(0, __builtin_bit_cast(int, v), 0x121, 0xf, 0xf, true);
    v = fmaxf(v, __builtin_bit_cast(float, ti));
    return v;
}
__device__ __forceinline__ float red16_sum(float v) {
    int ti;
    ti = __builtin_amdgcn_update_dpp(0, __builtin_bit_cast(int, v), 0x128, 0xf, 0xf, true);
    v += __builtin_bit_cast(float, ti);
    ti = __builtin_amdgcn_update_dpp(0, __builtin_bit_cast(int, v), 0x124, 0xf, 0xf, true);
    v += __builtin_bit_cast(float, ti);
    ti = __builtin_amdgcn_update_dpp(0, __builtin_bit_cast(int, v), 0x122, 0xf, 0xf, true);
    v += __builtin_bit_cast(float, ti);
    ti = __builtin_amdgcn_update_dpp(0, __builtin_bit_cast(int, v), 0x121, 0xf, 0xf, true);
    v += __builtin_bit_cast(float, ti);
    return v;
}

// ---------------------------------------------------------------------------
// K0all: ALL prep work in one launch (was 4 kernels -> kills 3 launch gaps
// and surfaces prep time in top-5 profiling).  blockIdx ranges:
//   [0,4224)       H prep   (22 x 3 x 64 tiles of 64u x 64h)
//   [4224,5632)    X prep   (22 x 64 tiles of 64t x 96x)
//   [5632,6760)    W2 + W1  (1128 x 256 = 288,768 tasks, exact)
// LDS transposes use XOR column swizzle (store col r ^ 8*((row>>3)&7)):
// round-11's linear layouts had 8-way (H) / 12-way (X) write conflicts —
// bank index was independent of the varying lane bits (stride ≡ 0 mod 32
// dwords forced by 16B-aligned read chunks); the XOR restores 8 distinct
// banks while keeping reads contiguous 16B.
// ---------------------------------------------------------------------------
__global__ __launch_bounds__(256) void k0_all(const float* __restrict__ Hg,
                                              u16* __restrict__ Hh,
                                              u16* __restrict__ Hl,
                                              u16* __restrict__ Hth,
                                              const float* __restrict__ Xg,
                                              u16* __restrict__ Xth,
                                              u16* __restrict__ Xtl,
                                              const float* __restrict__ W2g,
                                              u16* __restrict__ W2h,
                                              u16* __restrict__ W2l,
                                              const float* __restrict__ W1g,
                                              u16* __restrict__ W1th,
                                              u16* __restrict__ W1tl) {
    __shared__ __align__(16) u16 sb[2][96][72];   // 27,648 B
    const int tid = threadIdx.x;
    const int L = blockIdx.x;

    if (L < 4224) {
        // ---------------- H prep: tile (u0, h0, b) ----------------
        const int bx = L % 22, by = (L / 22) % 3, b = L / 66;
        const int u0 = bx * 64, h0 = by * 64;
        u16 (*til)[72] = sb[0];                   // [64][72] used
#pragma unroll
        for (int i = 0; i < 2; i++) {
            int task = i * 256 + tid;             // 0..511
            int r = task >> 3;                    // u row 0..63
            int g = task & 7;                     // h group of 8
            int u = u0 + r;
            float4 va = make_float4(0.f, 0.f, 0.f, 0.f), vb = va;
            if (u < T_) {
                const float* p = Hg + ((size_t)b * T_ + u) * HD_ + h0 + g * 8;
                va = *(const float4*)p;
                vb = *(const float4*)(p + 4);
            }
            float f[8] = {va.x, va.y, va.z, va.w, vb.x, vb.y, vb.z, vb.w};
            u16 hi[8], lo[8];
#pragma unroll
            for (int k = 0; k < 8; k++) {
                hi[k] = f2bf(f[k]);
                lo[k] = f2bf(f[k] - bf2f(hi[k]));
            }
            if (u < T_) {
                size_t base = ((size_t)b * T_ + u) * HD_ + h0 + g * 8;
                *(uint4*)(Hh + base) = *(const uint4*)hi;
                *(uint4*)(Hl + base) = *(const uint4*)lo;
            }
            const int rs = r ^ (g * 8);           // XOR swizzle ((h>>3)&7 == g)
#pragma unroll
            for (int k = 0; k < 8; k++) til[g * 8 + k][rs] = hi[k];
        }
        __syncthreads();
#pragma unroll
        for (int i = 0; i < 2; i++) {
            int task = i * 256 + tid;             // 0..511
            int hh = task >> 3;                   // h row 0..63
            int ug = task & 7;                    // logical u group of 8
            int q  = ug ^ (hh >> 3);              // physical chunk
            int ub = u0 + ug * 8;
            uint4 v = *(const uint4*)&til[hh][q * 8];
            u16* dst = Hth + ((size_t)b * HD_ + h0 + hh) * TP_ + ub;
            if (ub + 8 <= T_) {
                *(uint4*)dst = v;
            } else if (ub < TP_) {
                // tail: valid hi for u<T_, zeros for the pad (NaN insurance)
                const u16* pv = (const u16*)&v;
#pragma unroll
                for (int k = 0; k < 8; k++)
                    if (ub + k < TP_) dst[k] = (ub + k < T_) ? pv[k] : (u16)0;
            }
        }
    } else if (L < 5632) {
        // ---------------- X prep: tile (t0, b) ----------------
        const int j = L - 4224;
        const int t0 = (j % 22) * 64, b = j / 22;
        u16 (*tih)[72] = sb[0];
        u16 (*tlo)[72] = sb[1];
#pragma unroll
        for (int i = 0; i < 6; i++) {
            int task = i * 256 + tid;             // 0..1535
            int r = task / 24, xg = task % 24;    // r: t-row, xg: x group of 4
            float4 v = make_float4(0.f, 0.f, 0.f, 0.f);
            if (t0 + r < T_)
                v = *(const float4*)(Xg + ((size_t)b * T_ + t0 + r) * XD_ + xg * 4);
            float f[4] = {v.x, v.y, v.z, v.w};
            const int rs = r ^ (((xg >> 1) & 7) * 8);   // (x>>3)&7 == (xg>>1)&7
#pragma unroll
            for (int k = 0; k < 4; k++) {
                u16 hi = f2bf(f[k]);
                tih[xg * 4 + k][rs] = hi;
                tlo[xg * 4 + k][rs] = f2bf(f[k] - bf2f(hi));
            }
        }
        __syncthreads();
#pragma unroll
        for (int i = 0; i < 6; i++) {
            int id = i * 256 + tid;
            int buf = (id >= 768);
            int cid = buf ? id - 768 : id;
            int x = cid >> 3, col = cid & 7;
            int q = col ^ ((x >> 3) & 7);
            uint4 v = *(const uint4*)&(buf ? tlo : tih)[x][q * 8];
            u16* dst = (buf ? Xtl : Xth) + ((size_t)b * XD_ + x) * TP2_ + t0 + col * 8;
            *(uint4*)dst = v;
        }
    } else {
        // ---------------- W2 + W1 prep (exact 1128 x 256 tasks) ----------------
        const int j = L - 5632;                   // 0..1127
        const int i = j * 256 + tid;              // 0..288,767
        const int n2 = CP_ * (TP2_ / 2);          // 270,336
        if (i < n2) {
            int c = i / (TP2_ / 2), tc = i % (TP2_ / 2);
            int t = tc * 2;
            float v0 = 0.f, v1 = 0.f;
            if (c < CN_) {
                if (t < T_)     v0 = W2g[(size_t)c * T_ + t];
                if (t + 1 < T_) v1 = W2g[(size_t)c * T_ + t + 1];
            }
            u16 h0 = f2bf(v0), h1 = f2bf(v1);
            u16 l0 = f2bf(v0 - bf2f(h0)), l1 = f2bf(v1 - bf2f(h1));
            ((u32*)W2h)[i] = (u32)h0 | ((u32)h1 << 16);
            ((u32*)W2l)[i] = (u32)l0 | ((u32)l1 << 16);
        } else {
            int i1 = i - n2;                      // 0..18,431
            int h = i1 / XD_, x = i1 % XD_;
            float v = W1g[(size_t)x * HD_ + h];
            u16 hi = f2bf(v);
            W1th[i1] = hi;
            W1tl[i1] = f2bf(v - bf2f(hi));
        }
    }
}

// ---------------------------------------------------------------------------
// K12: unchanged (passed; gld_lds + counted vmcnt + dbuf).
// ---------------------------------------------------------------------------
__global__ __launch_bounds__(256, 1) void k12_mfma(const u16* __restrict__ W2h,
                                                   const u16* __restrict__ W2l,
                                                   const u16* __restrict__ Xth,
                                                   const u16* __restrict__ Xtl,
                                                   const u16* __restrict__ W1th,
                                                   const u16* __restrict__ W1tl,
                                                   u32* __restrict__ Ysi) {
    __shared__ __align__(16) u16 smem[49152];   // 96 KB = 2 bufs x 4 arrays x 96x64
    float* sZ = (float*)smem;                   // phase 2: 96 x 100 fp32 (38.4 KB, buf0 only)

    const int tid  = threadIdx.x;
    const int lane = tid & 63;
    const int w    = tid >> 6;            // 0..3: wave id == staging array id
    const int tx   = lane & 15;
    const int quad = lane >> 4;
    const int wr   = w >> 1;              // c-half (48 rows)
    const int wc2  = w & 1;               // x-half (48 cols)
    const int L    = blockIdx.x;
    const int xcd  = L & 7;
    const int slot = L >> 3;              // 0..31
    const int b    = xcd * 8 + (slot >> 2);
    const int c0   = (slot & 3) * 96;

    const u16* gsrc;
    size_t rowstart;
    if (w == 0)      { gsrc = W2h; rowstart = (size_t)c0; }
    else if (w == 1) { gsrc = W2l; rowstart = (size_t)c0; }
    else if (w == 2) { gsrc = Xth; rowstart = (size_t)b * XD_; }
    else             { gsrc = Xtl; rowstart = (size_t)b * XD_; }
    const int jg = (lane & 7) ^ ((lane >> 3) & 7);   // pre-swizzled source group

#define STAGE(bufsel, kk)                                                         \
    {                                                                             \
        u16* lb = smem + (bufsel) * 24576 + w * 6144;                             \
        _Pragma("unroll")                                                         \
        for (int i_ = 0; i_ < 12; i_++) {                                         \
            int row_ = i_ * 8 + (lane >> 3);                                      \
            const u16* gp_ = gsrc + (rowstart + row_) * TP2_ + (kk) + jg * 8;     \
            __builtin_amdgcn_global_load_lds(                                     \
                (const __attribute__((address_space(1))) u32*)(const void*)gp_,   \
                (__attribute__((address_space(3))) u32*)(void*)(lb + i_ * 512),   \
                16, 0, 0);                                                        \
        }                                                                         \
    }

    f32x4 accZ[3][3];
#pragma unroll
    for (int i = 0; i < 3; i++)
#pragma unroll
        for (int j = 0; j < 3; j++) accZ[i][j] = (f32x4){0.f, 0.f, 0.f, 0.f};

    STAGE(0, 0);
    for (int s = 0; s < 22; s++) {
        __builtin_amdgcn_sched_barrier(0);
        if (s < 21) {
            STAGE((s + 1) & 1, (s + 1) * 64);
            asm volatile("s_waitcnt vmcnt(12)" ::: "memory");  // cur tile landed
        } else {
            asm volatile("s_waitcnt vmcnt(0)" ::: "memory");
        }
        __builtin_amdgcn_s_barrier();
        __builtin_amdgcn_sched_barrier(0);
        const u16* bufp = smem + (s & 1) * 24576;
#pragma unroll
        for (int ks2 = 0; ks2 < 2; ks2++) {
            const int G = ks2 * 4 + quad;
            bf16x8 ah[3], al[3], bh3[3], bl3[3];
#pragma unroll
            for (int am = 0; am < 3; am++) {
                int row = wr * 48 + am * 16 + tx;
                int off = row * 64 + (G ^ (row & 7)) * 8;
                ah[am] = *(const bf16x8*)(bufp + off);
                al[am] = *(const bf16x8*)(bufp + 6144 + off);
            }
#pragma unroll
            for (int bn = 0; bn < 3; bn++) {
                int row = wc2 * 48 + bn * 16 + tx;
                int off = row * 64 + (G ^ (row & 7)) * 8;
                bh3[bn] = *(const bf16x8*)(bufp + 12288 + off);
                bl3[bn] = *(const bf16x8*)(bufp + 18432 + off);
            }
#pragma unroll
            for (int am = 0; am < 3; am++)
#pragma unroll
                for (int bn = 0; bn < 3; bn++) {
                    accZ[am][bn] = __builtin_amdgcn_mfma_f32_16x16x32_bf16(ah[am], bh3[bn], accZ[am][bn], 0, 0, 0);
                    accZ[am][bn] = __builtin_amdgcn_mfma_f32_16x16x32_bf16(ah[am], bl3[bn], accZ[am][bn], 0, 0, 0);
                    accZ[am][bn] = __builtin_amdgcn_mfma_f32_16x16x32_bf16(al[am], bh3[bn], accZ[am][bn], 0, 0, 0);
                }
        }
        asm volatile("s_waitcnt lgkmcnt(0)" ::: "memory");
        __builtin_amdgcn_sched_barrier(0);
        __builtin_amdgcn_s_barrier();
    }
#undef STAGE

    __builtin_amdgcn_sched_barrier(0);
#pragma unroll
    for (int am = 0; am < 3; am++)
#pragma unroll
        for (int bn = 0; bn < 3; bn++)
#pragma unroll
            for (int r = 0; r < 4; r++)
                sZ[(wr * 48 + am * 16 + quad * 4 + r) * 100 + wc2 * 48 + bn * 16 + tx] = accZ[am][bn][r];
    __syncthreads();

    bf16x8 A2h[3][3], A2l[3][3];
#pragma unroll
    for (int am = 0; am < 3; am++)
#pragma unroll
        for (int ks = 0; ks < 3; ks++) {
            const float* zrow = sZ + (wr * 48 + am * 16 + tx) * 100 + ks * 32 + quad * 8;
            bf16x8 vh, vl;
#pragma unroll
            for (int j = 0; j < 8; j++) {
                float v = zrow[j];
                u16 hi = f2bf(v);
                vh[j] = (short)hi;
                vl[j] = (short)f2bf(v - bf2f(hi));
            }
            A2h[am][ks] = vh; A2l[am][ks] = vl;
        }

    f32x4 accY[3][6];
#pragma unroll
    for (int i = 0; i < 3; i++)
#pragma unroll
        for (int j = 0; j < 6; j++) accY[i][j] = (f32x4){0.f, 0.f, 0.f, 0.f};
#pragma unroll
    for (int hn = 0; hn < 6; hn++) {
        const int hrow = wc2 * 96 + hn * 16 + tx;
#pragma unroll
        for (int ks = 0; ks < 3; ks++) {
            bf16x8 bh = *(const bf16x8*)(W1th + (size_t)hrow * XD_ + ks * 32 + quad * 8);
            bf16x8 bl = *(const bf16x8*)(W1tl + (size_t)hrow * XD_ + ks * 32 + quad * 8);
#pragma unroll
            for (int am = 0; am < 3; am++) {
                accY[am][hn] = __builtin_amdgcn_mfma_f32_16x16x32_bf16(A2h[am][ks], bh, accY[am][hn], 0, 0, 0);
                accY[am][hn] = __builtin_amdgcn_mfma_f32_16x16x32_bf16(A2h[am][ks], bl, accY[am][hn], 0, 0, 0);
                accY[am][hn] = __builtin_amdgcn_mfma_f32_16x16x32_bf16(A2l[am][ks], bh, accY[am][hn], 0, 0, 0);
            }
        }
    }

#pragma unroll
    for (int am = 0; am < 3; am++)
#pragma unroll
        for (int r = 0; r < 4; r++) {
            int c = c0 + wr * 48 + am * 16 + quad * 4 + r;
            if (c < CN_) {
                size_t base = ((size_t)b * CN_ + c) * HD_;
#pragma unroll
                for (int hn = 0; hn < 6; hn++) {
                    float y = SCALE_ * accY[am][hn][r];
                    u16 hi = f2bf(y);
                    u16 lo = f2bf(y - bf2f(hi));
                    Ysi[base + wc2 * 96 + hn * 16 + tx] = (u32)hi | ((u32)lo << 16);
                }
            }
        }
}

// ---------------------------------------------------------------------------
// K3: round-8 symmetric 12-wave version (proven 73.4 µs), unchanged.
// ---------------------------------------------------------------------------
__global__ __launch_bounds__(768, 3) void k3_mfma(const u32* __restrict__ Ysi,
                                                  const u16* __restrict__ Hh,
                                                  const u16* __restrict__ Hl,
                                                  const u16* __restrict__ Hth,
                                                  float* __restrict__ Op,
                                                  float* __restrict__ Ml,
                                                  float* __restrict__ Ll) {
    __shared__ __align__(16) u16 smem[44544];   // 89,088 B: 73,728 H-dbuf + 15,360 sP

    const int tid  = threadIdx.x;
    const int lane = tid & 63;
    const int w    = tid >> 6;            // 0..11
    const int tx   = lane & 15;
    const int quad = lane >> 4;
    const int L    = blockIdx.x;
    const int xcd  = L & 7;
    const int slot = L >> 3;              // 0..31
    const int gp   = xcd * 16 + (slot >> 1);   // (b,sp) pair, 0..127
    const int ct   = slot & 1;                 // c-tile half (192 rows)
    const int b    = gp >> 1;
    const int sp   = gp & 1;
    const int c0   = ct * 192;
    const int us   = sp * TH_, ue = us + TH_;

    // ---- A-operand from interleaved Ysi (unpack once)
    bf16x8 Ah[6], Al[6];
    const int ar = c0 + w * 16 + tx;
    if (ar < CN_) {
        const u32* yi = Ysi + ((size_t)b * CN_ + ar) * HD_;
#pragma unroll
        for (int ks = 0; ks < 6; ks++) {
            u32 vv[8];
            *(uint4*)&vv[0] = *(const uint4*)(yi + ks * 32 + quad * 8);
            *(uint4*)&vv[4] = *(const uint4*)(yi + ks * 32 + quad * 8 + 4);
            bf16x8 hh, ll;
#pragma unroll
            for (int j = 0; j < 8; j++) {
                hh[j] = (short)(vv[j] & 0xffffu);
                ll[j] = (short)(vv[j] >> 16);
            }
            Ah[ks] = hh; Al[ks] = ll;
        }
    } else {
#pragma unroll
        for (int ks = 0; ks < 6; ks++) { Ah[ks] = (bf16x8)0; Al[ks] = (bf16x8)0; }
    }

    float m_s[4], l_s[4];
    f32x4 accO[12];
#pragma unroll
    for (int r = 0; r < 4; r++) { m_s[r] = -1e30f; l_s[r] = 0.f; }
#pragma unroll
    for (int j = 0; j < 12; j++) accO[j] = (f32x4){0.f, 0.f, 0.f, 0.f};

    // ---- per-lane staging descriptors: 36 gld_lds/iter, 3 per wave.
    const char* srcp[3];
    u32 off0[3];
    const u32 incw = (u32)__builtin_amdgcn_readfirstlane((w < 8) ? (32 * HD_ * 2) : 64);
#pragma unroll
    for (int j = 0; j < 3; j++) {
        int k = w * 3 + j;
        u32 o;
        if (k < 24) {
            int arr = (k < 12) ? 0 : 1;
            int ii  = k - arr * 12;
            int cid = ii * 64 + lane;          // 0..767
            int u   = cid / 24, c1 = cid % 24;
            int c   = (c1 & ~7) | ((c1 & 7) ^ ((u >> 1) & 7));
            const u16* basep = (arr == 0 ? Hh : Hl) + (size_t)b * T_ * HD_;
            srcp[j] = (const char*)basep + ((size_t)(us + u) * HD_ + c * 8) * 2;
            o = (u32)(arr * 24576 + ii * 1024);
        } else {
            int ii  = k - 24;
            int cid = ii * 64 + lane;          // 0..767
            int h   = cid >> 2, c2 = cid & 3;
            int c   = c2 ^ ((h >> 2) & 3);
            const u16* basep = Hth + (size_t)b * HD_ * TP_;
            srcp[j] = (const char*)basep + ((size_t)h * TP_ + us + c * 8) * 2;
            o = (u32)(49152 + ii * 1024);
        }
        off0[j] = (u32)__builtin_amdgcn_readfirstlane((int)o);
    }

#define STAGE3(bufsel)                                                            \
    {                                                                             \
        _Pragma("unroll")                                                         \
        for (int j_ = 0; j_ < 3; j_++) {                                          \
            __builtin_amdgcn_global_load_lds(                                     \
                (const __attribute__((address_space(1))) u32*)(const void*)srcp[j_], \
                (__attribute__((address_space(3))) u32*)(void*)((char*)smem + off0[j_] + (bufsel) * 12288), \
                16, 0, 0);                                                        \
            srcp[j_] += incw;                                                     \
        }                                                                         \
    }

    u16* sPb = smem + 36864;                   // 192 x 40 u16 (byte 73,728)

    STAGE3(0);                                  // tile 0 -> buf 0
    for (int t = 0; t < 22; t++) {
        const int u0  = us + t * 32;
        const int buf = t & 1;
        __builtin_amdgcn_sched_barrier(0);
        if (t < 21) {
            STAGE3(buf ^ 1);                    // tile t+1 -> other buf
            asm volatile("s_waitcnt vmcnt(3)" ::: "memory");   // tile t landed
        } else {
            asm volatile("s_waitcnt vmcnt(0)" ::: "memory");
        }
        __builtin_amdgcn_s_barrier();
        __builtin_amdgcn_sched_barrier(0);

        const u16* Hhb = smem + buf * 6144;
        const u16* Hlb = smem + 12288 + buf * 6144;
        const u16* Htb = smem + 24576 + buf * 6144;

        // ---- GEMM1: S[c][u], K=192, split-bf16 (hi*hi + hi*lo + lo*hi)
        f32x4 s0a = {0.f, 0.f, 0.f, 0.f}, s1a = {0.f, 0.f, 0.f, 0.f};
        f32x4 s0b = {0.f, 0.f, 0.f, 0.f}, s1b = {0.f, 0.f, 0.f, 0.f};
        const int xr = (tx >> 1) & 7;           // same for row tx and 16+tx
        __builtin_amdgcn_s_setprio(1);
#pragma unroll
        for (int ks = 0; ks < 6; ks++) {
            const int cc = ks * 4 + quad;
            const int cs = (cc & ~7) | ((cc & 7) ^ xr);
            const int ro0 = tx * 192 + cs * 8;
            const int ro1 = (16 + tx) * 192 + cs * 8;
            bf16x8 bh0 = *(const bf16x8*)(Hhb + ro0);
            bf16x8 bl0 = *(const bf16x8*)(Hlb + ro0);
            bf16x8 bh1 = *(const bf16x8*)(Hhb + ro1);
            bf16x8 bl1 = *(const bf16x8*)(Hlb + ro1);
            s0a = __builtin_amdgcn_mfma_f32_16x16x32_bf16(Ah[ks], bh0, s0a, 0, 0, 0);
            s1a = __builtin_amdgcn_mfma_f32_16x16x32_bf16(Ah[ks], bl0, s1a, 0, 0, 0);
            s1a = __builtin_amdgcn_mfma_f32_16x16x32_bf16(Al[ks], bh0, s1a, 0, 0, 0);
            s0b = __builtin_amdgcn_mfma_f32_16x16x32_bf16(Ah[ks], bh1, s0b, 0, 0, 0);
            s1b = __builtin_amdgcn_mfma_f32_16x16x32_bf16(Ah[ks], bl1, s1b, 0, 0, 0);
            s1b = __builtin_amdgcn_mfma_f32_16x16x32_bf16(Al[ks], bh1, s1b, 0, 0, 0);
        }
        __builtin_amdgcn_s_setprio(0);
        float sv0[4], sv1[4];
        const bool okA = (u0 + tx) < ue, okB = (u0 + 16 + tx) < ue;
#pragma unroll
        for (int r = 0; r < 4; r++) {
            sv0[r] = okA ? (s0a[r] + s1a[r]) : -1e30f;
            sv1[r] = okB ? (s0b[r] + s1b[r]) : -1e30f;
        }

        // ---- online softmax; 16-lane reductions via DPP (VALU, no DS)
        float alpha[4];
#pragma unroll
        for (int r = 0; r < 4; r++) {
            float mx = red16_max(fmaxf(sv0[r], sv1[r]));
            float mn = fmaxf(m_s[r], mx);
            alpha[r] = __expf(m_s[r] - mn);
            float p0 = __expf(sv0[r] - mn);
            float p1 = __expf(sv1[r] - mn);
            sPb[(w * 16 + quad * 4 + r) * 40 + tx]      = f2bf(p0);
            sPb[(w * 16 + quad * 4 + r) * 40 + 16 + tx] = f2bf(p1);
            float s = red16_sum(p0 + p1);
            l_s[r] = l_s[r] * alpha[r] + s;
            m_s[r] = mn;
        }
        f32x4 alv = {alpha[0], alpha[1], alpha[2], alpha[3]};
#pragma unroll
        for (int j = 0; j < 12; j++) accO[j] *= alv;

        // ---- PV: O += P * H, K=32.  sP rows are wave-private (in-order DS).
        bf16x8 pa = *(const bf16x8*)(sPb + (w * 16 + tx) * 40 + quad * 8);
        const int ctq = quad ^ ((tx >> 2) & 3);
        __builtin_amdgcn_s_setprio(1);
#pragma unroll
        for (int j = 0; j < 12; j++) {
            bf16x8 hb = *(const bf16x8*)(Htb + (j * 16 + tx) * 32 + ctq * 8);
            accO[j] = __builtin_amdgcn_mfma_f32_16x16x32_bf16(pa, hb, accO[j], 0, 0, 0);
        }
        __builtin_amdgcn_s_setprio(0);

        // all LDS reads of buf done before any wave stages into it next iter
        asm volatile("s_waitcnt lgkmcnt(0)" ::: "memory");
        __builtin_amdgcn_sched_barrier(0);
        __builtin_amdgcn_s_barrier();
    }
#undef STAGE3

#pragma unroll
    for (int r = 0; r < 4; r++) {
        int c = c0 + w * 16 + quad * 4 + r;
        if (c < CN_) {
            float* orow = Op + (((size_t)sp * B_ + b) * CN_ + c) * HD_;
#pragma unroll
            for (int j = 0; j < 12; j++) orow[j * 16 + tx] = accO[j][r];
            if (tx == 0) {
                size_t mi = ((size_t)sp * B_ + b) * CN_ + c;
                Ml[mi] = m_s[r];
                Ll[mi] = l_s[r];
            }
        }
    }
}

// ---------------------------------------------------------------------------
// K4: merge the two u-half partials — float4-vectorized grid-stride.
// ---------------------------------------------------------------------------
__global__ __launch_bounds__(256) void k_merge(const float* __restrict__ Op,
                                               const float* __restrict__ Ml,
                                               const float* __restrict__ Ll,
                                               float* __restrict__ out) {
    const int total = B_ * CN_ * (HD_ / 4);     // 1,059,840 float4 tasks
    for (int i = blockIdx.x * 256 + threadIdx.x; i < total; i += gridDim.x * 256) {
        int f  = i % (HD_ / 4);
        int bc = i / (HD_ / 4);                 // b*CN_ + c
        const size_t i0 = (size_t)bc;
        const size_t i1 = (size_t)B_ * CN_ + i0;
        float m0 = Ml[i0], m1 = Ml[i1];
        float l0 = Ll[i0], l1 = Ll[i1];
        float M  = fmaxf(m0, m1);
        float e0 = __expf(m0 - M), e1 = __expf(m1 - M);
        float inv = 1.0f / (l0 * e0 + l1 * e1);
        float4 o0 = *(const float4*)(Op + i0 * HD_ + f * 4);
        float4 o1 = *(const float4*)(Op + i1 * HD_ + f * 4);
        float4 r;
        r.x = (o0.x * e0 + o1.x * e1) * inv;
        r.y = (o0.y * e0 + o1.y * e1) * inv;
        r.z = (o0.z * e0 + o1.z * e1) * inv;
        r.w = (o0.w * e0 + o1.w * e1) * inv;
        *(float4*)(out + i0 * HD_ + f * 4) = r;
    }
}

// ---------------------------------------------------------------------------
extern "C" void kernel_launch(void* const* d_in, const int* in_sizes, int n_in,
                              void* d_out, int out_size, void* d_ws, size_t ws_size,
                              hipStream_t stream) {
    const float* X  = (const float*)d_in[0];
    const float* H  = (const float*)d_in[1];
    const float* W1 = (const float*)d_in[2];
    const float* W2 = (const float*)d_in[3];
    float* out = (float*)d_out;

    char* ws = (char*)d_ws;
    u32*   Ysi  = (u32*)(ws);                    //  16,957,440 (interleaved hi|lo)
    u16*   Hh   = (u16*)(ws + 16957440);         //  33,914,880
    u16*   Hl   = (u16*)(ws + 50872320);         //  33,914,880
    u16*   Hth  = (u16*)(ws + 84787200);         //  34,209,792
    u16*   Xth  = (u16*)(ws + 118996992);        //  17,301,504  (aliased by Op later)
    u16*   Xtl  = (u16*)(ws + 136298496);        //  17,301,504
    float* Op   = (float*)(ws + 118996992);      //  33,914,880  (aliases Xth+Xtl; k12 done first)
    u16*   W2h  = (u16*)(ws + 153600000);        //   1,081,344
    u16*   W2l  = (u16*)(ws + 154681344);        //   1,081,344
    u16*   W1th = (u16*)(ws + 155762688);        //      36,864
    u16*   W1tl = (u16*)(ws + 155799552);        //      36,864
    float* Ml   = (float*)(ws + 155836416);      //     176,640
    float* Ll   = (float*)(ws + 156013056);      //     176,640  -> end 156,189,696

    k0_all  <<<dim3(6760),      256, 0, stream>>>(H, Hh, Hl, Hth,
                                                  X, Xth, Xtl,
                                                  W2, W2h, W2l,
                                                  W1, W1th, W1tl);
    k12_mfma<<<dim3(256),       256, 0, stream>>>(W2h, W2l, Xth, Xtl, W1th, W1tl, Ysi);
    k3_mfma <<<dim3(256),       768, 0, stream>>>(Ysi, Hh, Hl, Hth, Op, Ml, Ll);
    k_merge <<<dim3(2048),      256, 0, stream>>>(Op, Ml, Ll, out);
}